// Round 15
// baseline (546.495 us; speedup 1.0000x reference)
//
#include <hip/hip_runtime.h>

#define NN 100000
#define NE 600000
#define DIM 128
#define NG 256
#define NGRP 6250   // NN/16
#define NB_SCAN 391  // ceil(NN/256)
#define FILL_NB 2344 // ceil(NE/256)
#define PREP_NB 128
#define EMB_NB 25000 // NN/4

typedef __attribute__((ext_vector_type(8))) short short8_t;
typedef __attribute__((ext_vector_type(4))) float f32x4;

__device__ __forceinline__ ushort f2bf(float f) {
  unsigned u = __float_as_uint(f);
  unsigned r = (u + 0x7fffu + ((u >> 16) & 1u)) >> 16;
  return (ushort)r;
}
__device__ __forceinline__ float bf2f(ushort h) {
  return __uint_as_float(((unsigned)h) << 16);
}

// ---------------- CSR: degree ----------------
__global__ __launch_bounds__(256) void deg_int_kernel(const int* __restrict__ dst,
                                                      int* __restrict__ degi) {
  int e = blockIdx.x * 256 + threadIdx.x;
  if (e < NE) atomicAdd(degi + dst[e], 1);
}

// ---------------- CSR: per-block scan ----------------
__global__ __launch_bounds__(256) void scan1_kernel(const int* __restrict__ degi,
                                                    int* __restrict__ excl,
                                                    int* __restrict__ bsum) {
  __shared__ int tmp[256];
  int t = threadIdx.x;
  int i = blockIdx.x * 256 + t;
  int v = (i < NN) ? degi[i] : 0;
  int val = v;
  tmp[t] = val;
  __syncthreads();
  for (int off = 1; off < 256; off <<= 1) {
    int add = (t >= off) ? tmp[t - off] : 0;
    __syncthreads();
    val += add;
    tmp[t] = val;
    __syncthreads();
  }
  if (i < NN) excl[i] = val - v;
  if (t == 255) bsum[blockIdx.x] = val;
}

// ---------------- CSR: block-offset + row_off + cursor ----------------
__global__ __launch_bounds__(256) void scan23_kernel(const int* __restrict__ excl,
                                                     const int* __restrict__ bsum,
                                                     int* __restrict__ row_off,
                                                     int* __restrict__ cursor) {
  __shared__ int sh[256];
  int blk = blockIdx.x;
  int t = threadIdx.x;
  int partial = 0;
  for (int j = t; j < blk; j += 256) partial += bsum[j];
  sh[t] = partial;
  __syncthreads();
  for (int off = 128; off; off >>= 1) {
    if (t < off) sh[t] += sh[t + off];
    __syncthreads();
  }
  int base = sh[0];
  int i = blk * 256 + t;
  if (i < NN) {
    int r = excl[i] + base;
    row_off[i] = r;
    cursor[i] = r;
  }
  if (i == NN) row_off[NN] = NE;
}

// ---------------- device bodies for the mega kernel ----------------
__device__ __forceinline__ void fill_body(int bid, int t, const int* __restrict__ src,
                                          const int* __restrict__ dst,
                                          int* __restrict__ cursor,
                                          int* __restrict__ csr_src) {
  int e = bid * 256 + t;
  if (e < NE) {
    int d = dst[e];
    int slot = atomicAdd(cursor + d, 1);
    csr_src[slot] = src[e];
  }
}

// wp layout: [p][hl][j][ht][lane][8]; k = p*64 + j*32 + lq*4 + (e&3) + 16*(e>>2);
// k<128 -> wl (agg term, p=0,1), k>=128 -> wr (self term, p=2,3).
__device__ __forceinline__ void prep_body(int idx, const float* __restrict__ wl,
                                          const float* __restrict__ wr,
                                          ushort* __restrict__ wp) {
  int e = idx & 7;
  int lane = (idx >> 3) & 63;
  int ht = (idx >> 9) & 7;
  int j = (idx >> 12) & 1;
  int p = (idx >> 13) & 3;
  int h = ht * 16 + (lane & 15);
  int lq = lane >> 4;
  int k = p * 64 + j * 32 + lq * 4 + (e & 3) + 16 * (e >> 2);
  float v = (k < 128) ? wl[h * 128 + k] : wr[h * 128 + (k - 128)];
  ushort hi = f2bf(v);
  ushort lo = f2bf(v - bf2f(hi));
  wp[(((p * 2 + 0) * 2 + j) * 8 + ht) * 512 + lane * 8 + e] = hi;
  wp[(((p * 2 + 1) * 2 + j) * 8 + ht) * 512 + lane * 8 + e] = lo;
}

__device__ __forceinline__ void embed_body(int bid, int t, const int* __restrict__ x_idx,
                                           const float* __restrict__ emb,
                                           const float* __restrict__ g,
                                           const float* __restrict__ b,
                                           float* __restrict__ out) {
  int wave = t >> 6;
  int lane = t & 63;
  int n = bid * 4 + wave;
  if (n >= NN) return;
  int idx = x_idx[n];
  float2 v = ((const float2*)(emb + (size_t)idx * DIM))[lane];
  float s = v.x + v.y;
  float sq = v.x * v.x + v.y * v.y;
  for (int off = 32; off; off >>= 1) {
    s += __shfl_xor(s, off);
    sq += __shfl_xor(sq, off);
  }
  float m = s * (1.0f / 128.0f);
  float var = sq * (1.0f / 128.0f) - m * m;
  float r = rsqrtf(var + 1e-5f);
  float2 gg = ((const float2*)g)[lane];
  float2 bb = ((const float2*)b)[lane];
  float2 o;
  o.x = (v.x - m) * r * gg.x + bb.x;
  o.y = (v.y - m) * r * gg.y + bb.y;
  ((float2*)(out + (size_t)n * DIM))[lane] = o;
}

// ---------------- mega kernel: fill | prep_w x2 | embed_ln ----------------
__global__ __launch_bounds__(256) void mega_kernel(
    const int* __restrict__ src, const int* __restrict__ dst,
    int* __restrict__ cursor, int* __restrict__ csr_src,
    const float* __restrict__ w0l, const float* __restrict__ w0r, ushort* __restrict__ wp0,
    const float* __restrict__ w1l, const float* __restrict__ w1r, ushort* __restrict__ wp1,
    const int* __restrict__ x_idx, const float* __restrict__ emb,
    const float* __restrict__ ln0g, const float* __restrict__ ln0b,
    float* __restrict__ x) {
  int bid = blockIdx.x;
  int t = threadIdx.x;
  if (bid < FILL_NB) {
    fill_body(bid, t, src, dst, cursor, csr_src);
  } else if (bid < FILL_NB + PREP_NB) {
    prep_body((bid - FILL_NB) * 256 + t, w0l, w0r, wp0);
  } else if (bid < FILL_NB + 2 * PREP_NB) {
    prep_body((bid - FILL_NB - PREP_NB) * 256 + t, w1l, w1r, wp1);
  } else {
    embed_body(bid - FILL_NB - 2 * PREP_NB, t, x_idx, emb, ln0g, ln0b, x);
  }
}

// ---------------- gather mean -> fragment-layout agg (4-wide edge MLP) --------
// af layout (ushort): [g16][jb(4)][lane(64)][hl(2)][e(8)], lane=(lq*16+l15),
// node n = g16*16+l15, k = jb*32 + lq*4 + (e&3) + 16*(e>>2).
// Accumulation order is kept strictly sequential (bit-identical to r14).
__global__ __launch_bounds__(256) void gather_mean_kernel(
    const int* __restrict__ row_off, const int* __restrict__ csr_src,
    const float* __restrict__ x, ushort* __restrict__ af) {
  int t = threadIdx.x;
  int q = t & 31;
  int node = blockIdx.x * 8 + (t >> 5);
  if (node >= NN) return;
  int beg = row_off[node], end = row_off[node + 1];
  float4 acc = make_float4(0.f, 0.f, 0.f, 0.f);
  int e = beg;
  for (; e + 4 <= end; e += 4) {
    int s0 = csr_src[e];
    int s1 = csr_src[e + 1];
    int s2 = csr_src[e + 2];
    int s3 = csr_src[e + 3];
    float4 v0 = ((const float4*)(x + (size_t)s0 * DIM))[q];
    float4 v1 = ((const float4*)(x + (size_t)s1 * DIM))[q];
    float4 v2 = ((const float4*)(x + (size_t)s2 * DIM))[q];
    float4 v3 = ((const float4*)(x + (size_t)s3 * DIM))[q];
    acc.x += v0.x; acc.y += v0.y; acc.z += v0.z; acc.w += v0.w;
    acc.x += v1.x; acc.y += v1.y; acc.z += v1.z; acc.w += v1.w;
    acc.x += v2.x; acc.y += v2.y; acc.z += v2.z; acc.w += v2.w;
    acc.x += v3.x; acc.y += v3.y; acc.z += v3.z; acc.w += v3.w;
  }
  for (; e < end; ++e) {
    int s = csr_src[e];
    float4 v = ((const float4*)(x + (size_t)s * DIM))[q];
    acc.x += v.x; acc.y += v.y; acc.z += v.z; acc.w += v.w;
  }
  float sc = 1.0f / fmaxf((float)(end - beg), 1.0f);
  acc.x *= sc; acc.y *= sc; acc.z *= sc; acc.w *= sc;
  ushort4 hi, lo;
  hi.x = f2bf(acc.x); lo.x = f2bf(acc.x - bf2f(hi.x));
  hi.y = f2bf(acc.y); lo.y = f2bf(acc.y - bf2f(hi.y));
  hi.z = f2bf(acc.z); lo.z = f2bf(acc.z - bf2f(hi.z));
  hi.w = f2bf(acc.w); lo.w = f2bf(acc.w - bf2f(hi.w));
  int g = node >> 4, l15n = node & 15;
  int jb = q >> 3, lqw = q & 3, ebase = q & 4;
  size_t base = (((size_t)g * 4 + jb) * 64 + lqw * 16 + l15n) * 16;
  *(ushort4*)(af + base + ebase) = hi;
  *(ushort4*)(af + base + 8 + ebase) = lo;
}

// ---------------- SAGE conv, TILE=64, af prefetched early ----------------
// out = relu([agg|x] @ Wcat^T + bl) (+ optional fused LN), fp32 out.
// Block = 64 nodes, 4 waves, each wave 16 nodes x 128 h. LDS 16 KB.
// af fragment loads (phases 2,3 inputs, LDS-independent) are issued FIRST so
// their latency hides under the staging + phases 0,1 MFMAs.
__global__ __launch_bounds__(256) void conv_mfma_kernel(
    const float* __restrict__ xln, const ushort* __restrict__ af,
    const ushort* __restrict__ wp, const float* __restrict__ bl,
    const float* __restrict__ lng, const float* __restrict__ lnb,
    float* __restrict__ out, int do_ln) {
  __shared__ ushort Xs[2][64 * 64];  // 16 KB
  const int t = threadIdx.x;
  const int lane = t & 63;
  const int wv = t >> 6;
  const int l15 = lane & 15;
  const int lq = lane >> 4;
  const int nbase = blockIdx.x * 64;

  // ---- early af prefetch (phases 2,3 A-operands) ----
  const int g = blockIdx.x * 4 + wv;
  short8_t pahi[4], palo[4];
#pragma unroll
  for (int jb = 0; jb < 4; ++jb) {
    if (g < NGRP) {
      size_t base = (((size_t)g * 4 + jb) * 64 + lane) * 16;
      pahi[jb] = *(const short8_t*)(af + base);
      palo[jb] = *(const short8_t*)(af + base + 8);
    } else {
      pahi[jb] = (short8_t){0, 0, 0, 0, 0, 0, 0, 0};
      palo[jb] = (short8_t){0, 0, 0, 0, 0, 0, 0, 0};
    }
  }

  f32x4 acc[8];
#pragma unroll
  for (int b = 0; b < 8; ++b) acc[b] = (f32x4){0.f, 0.f, 0.f, 0.f};

  const int srow = t >> 2;   // staging row 0..63
  const int sq4 = t & 3;     // quad group
  const int gn_s = nbase + srow;
  const bool sval = gn_s < NN;
  char* lds_hi = (char*)&Xs[0][0];
  char* lds_lo = (char*)&Xs[1][0];
  const int sswz = (srow & 7) << 4;

  // ======== phases 0,1: x self-half (staged), W slice pk = ph+2 ========
#pragma unroll 1
  for (int ph = 0; ph < 2; ++ph) {
    if (ph) __syncthreads();
    const int kb = ph * 64;
#pragma unroll
    for (int i = 0; i < 4; ++i) {
      int qd = i * 4 + sq4;
      float4 v = make_float4(0.f, 0.f, 0.f, 0.f);
      if (sval) v = *(const float4*)(xln + (size_t)gn_s * DIM + kb + qd * 4);
      int j = qd >> 3;
      int a = qd & 7;
      int inner = j * 64 + ((a < 4) ? a * 16 : (a - 4) * 16 + 8);
      int off = srow * 128 + inner;
      ushort4 hi, lo;
      hi.x = f2bf(v.x); lo.x = f2bf(v.x - bf2f(hi.x));
      hi.y = f2bf(v.y); lo.y = f2bf(v.y - bf2f(hi.y));
      hi.z = f2bf(v.z); lo.z = f2bf(v.z - bf2f(hi.z));
      hi.w = f2bf(v.w); lo.w = f2bf(v.w - bf2f(hi.w));
      *(ushort4*)(lds_hi + (off ^ sswz)) = hi;
      *(ushort4*)(lds_lo + (off ^ sswz)) = lo;
    }
    __syncthreads();
    const int pk = ph + 2;  // wr half of Wcat
#pragma unroll
    for (int j = 0; j < 2; ++j) {
      int row = wv * 16 + l15;
      int off = row * 128 + j * 64 + lq * 16;
      int sw = (row & 7) << 4;
      short8_t ahi = *(short8_t*)(lds_hi + (off ^ sw));
      short8_t alo = *(short8_t*)(lds_lo + (off ^ sw));
#pragma unroll
      for (int ht = 0; ht < 8; ++ht) {
        short8_t bhi = *(const short8_t*)(wp + (((pk * 2 + 0) * 2 + j) * 8 + ht) * 512 + lane * 8);
        short8_t blo = *(const short8_t*)(wp + (((pk * 2 + 1) * 2 + j) * 8 + ht) * 512 + lane * 8);
        acc[ht] = __builtin_amdgcn_mfma_f32_16x16x32_bf16(ahi, bhi, acc[ht], 0, 0, 0);
        acc[ht] = __builtin_amdgcn_mfma_f32_16x16x32_bf16(alo, bhi, acc[ht], 0, 0, 0);
        acc[ht] = __builtin_amdgcn_mfma_f32_16x16x32_bf16(ahi, blo, acc[ht], 0, 0, 0);
      }
    }
  }

  // ======== phases 2,3: agg half from prefetched fragments ========
#pragma unroll 1
  for (int ph = 2; ph < 4; ++ph) {
    const int pk = ph - 2;  // wl half of Wcat
#pragma unroll
    for (int j = 0; j < 2; ++j) {
      int jb = (ph & 1) * 2 + j;
      short8_t ahi = pahi[jb];
      short8_t alo = palo[jb];
#pragma unroll
      for (int ht = 0; ht < 8; ++ht) {
        short8_t bhi = *(const short8_t*)(wp + (((pk * 2 + 0) * 2 + j) * 8 + ht) * 512 + lane * 8);
        short8_t blo = *(const short8_t*)(wp + (((pk * 2 + 1) * 2 + j) * 8 + ht) * 512 + lane * 8);
        acc[ht] = __builtin_amdgcn_mfma_f32_16x16x32_bf16(ahi, bhi, acc[ht], 0, 0, 0);
        acc[ht] = __builtin_amdgcn_mfma_f32_16x16x32_bf16(alo, bhi, acc[ht], 0, 0, 0);
        acc[ht] = __builtin_amdgcn_mfma_f32_16x16x32_bf16(ahi, blo, acc[ht], 0, 0, 0);
      }
    }
  }

  // ======== epilogue: bias + relu (+ fused LN), fp32 row-major store ========
#pragma unroll
  for (int ht = 0; ht < 8; ++ht) {
    float bv = bl[ht * 16 + l15];
#pragma unroll
    for (int r = 0; r < 4; ++r) acc[ht][r] = fmaxf(acc[ht][r] + bv, 0.f);
  }
  if (do_ln) {
    float gg[8], bb[8];
#pragma unroll
    for (int ht = 0; ht < 8; ++ht) {
      gg[ht] = lng[ht * 16 + l15];
      bb[ht] = lnb[ht * 16 + l15];
    }
#pragma unroll
    for (int r = 0; r < 4; ++r) {
      float s = 0.f, sq = 0.f;
#pragma unroll
      for (int ht = 0; ht < 8; ++ht) {
        float v = acc[ht][r];
        s += v;
        sq += v * v;
      }
#pragma unroll
      for (int msk = 1; msk < 16; msk <<= 1) {
        s += __shfl_xor(s, msk);
        sq += __shfl_xor(sq, msk);
      }
      float m = s * (1.0f / 128.0f);
      float var = sq * (1.0f / 128.0f) - m * m;
      float rstd = rsqrtf(var + 1e-5f);
      int node = nbase + wv * 16 + lq * 4 + r;
      if (node < NN) {
#pragma unroll
        for (int ht = 0; ht < 8; ++ht)
          out[(size_t)node * DIM + ht * 16 + l15] =
              (acc[ht][r] - m) * rstd * gg[ht] + bb[ht];
      }
    }
  } else {
#pragma unroll
    for (int r = 0; r < 4; ++r) {
      int node = nbase + wv * 16 + lq * 4 + r;
      if (node < NN) {
#pragma unroll
        for (int ht = 0; ht < 8; ++ht)
          out[(size_t)node * DIM + ht * 16 + l15] = acc[ht][r];
      }
    }
  }
}

// ---------------- mean pool over sorted batch (short chunks, more TLP) --------
#define PCHUNK 32
__global__ __launch_bounds__(128) void pool_kernel(const float* __restrict__ x,
                                                   const int* __restrict__ batch,
                                                   float* __restrict__ pool,
                                                   float* __restrict__ cnt) {
  int f = threadIdx.x;
  int n0 = blockIdx.x * PCHUNK;
  float acc = 0.f;
  int cur = batch[n0];
  int runlen = 0;
  for (int i = 0; i < PCHUNK; ++i) {
    int n = n0 + i;
    if (n >= NN) break;
    int bg = batch[n];
    if (bg != cur) {
      atomicAdd(&pool[cur * DIM + f], acc);
      if (f == 0) atomicAdd(&cnt[cur], (float)runlen);
      acc = 0.f;
      runlen = 0;
      cur = bg;
    }
    acc += x[(size_t)n * DIM + f];
    runlen++;
  }
  if (runlen > 0) {
    atomicAdd(&pool[cur * DIM + f], acc);
    if (f == 0) atomicAdd(&cnt[cur], (float)runlen);
  }
}

// ---------------- MLP head ----------------
__global__ __launch_bounds__(128) void head_kernel(
    const float* __restrict__ pool, const float* __restrict__ cnt,
    const float* __restrict__ w1, const float* __restrict__ b1,
    const float* __restrict__ w2, const float* __restrict__ b2,
    float* __restrict__ out) {
  __shared__ float gsh[128];
  __shared__ float h[64];
  int g = blockIdx.x;
  int t = threadIdx.x;
  float ic = 1.0f / fmaxf(cnt[g], 1.0f);
  gsh[t] = pool[g * DIM + t] * ic;
  __syncthreads();
  if (t < 64) {
    float a = b1[t];
#pragma unroll 8
    for (int k = 0; k < 128; ++k) a += gsh[k] * w1[t * 128 + k];
    h[t] = fmaxf(a, 0.f);
  }
  __syncthreads();
  if (t < 2) {
    float a = b2[t];
#pragma unroll
    for (int k = 0; k < 64; ++k) a += h[k] * w2[t * 64 + k];
    out[g * 2 + t] = a;
  }
}

extern "C" void kernel_launch(void* const* d_in, const int* in_sizes, int n_in,
                              void* d_out, int out_size, void* d_ws, size_t ws_size,
                              hipStream_t stream) {
  const int* x_idx = (const int*)d_in[0];
  const int* eidx = (const int*)d_in[1];
  const int* batch = (const int*)d_in[2];
  const float* emb = (const float*)d_in[3];
  const float* ln0g = (const float*)d_in[4];
  const float* ln0b = (const float*)d_in[5];
  const float* w0l = (const float*)d_in[6];
  const float* b0l = (const float*)d_in[7];
  const float* w0r = (const float*)d_in[8];
  const float* ln1g = (const float*)d_in[9];
  const float* ln1b = (const float*)d_in[10];
  const float* w1l = (const float*)d_in[11];
  const float* b1l = (const float*)d_in[12];
  const float* w1r = (const float*)d_in[13];
  const float* mw1 = (const float*)d_in[14];
  const float* mb1 = (const float*)d_in[15];
  const float* mw2 = (const float*)d_in[16];
  const float* mb2 = (const float*)d_in[17];
  float* out = (float*)d_out;

  float* ws = (float*)d_ws;
  float* x = ws;                                   // NN*DIM fp32
  ushort* af = (ushort*)(x + (size_t)NN * DIM);    // NN*DIM*2 ushort (frag agg)
  float* pool = (float*)(af + (size_t)NN * DIM * 2);  // NG*DIM
  float* cnt = pool + (size_t)NG * DIM;            // NG
  int* degi = (int*)(cnt + NG);                    // NN (contig for one memset)
  int* excl = degi + NN;                           // NN
  int* row_off = excl + NN;                        // NN+1
  int* cursor = row_off + NN + 1;                  // NN
  int* bsum = cursor + NN;                         // 512
  int* csr_src = bsum + 512;                       // NE
  ushort* wp0 = (ushort*)(csr_src + NE);           // 65536 ushort each
  ushort* wp1 = wp0 + 65536;

  const int* src = eidx;
  const int* dst = eidx + NE;

  // one memset: pool + cnt + degi are contiguous
  hipMemsetAsync(pool, 0, ((size_t)NG * DIM + NG + NN) * sizeof(float), stream);

  deg_int_kernel<<<FILL_NB, 256, 0, stream>>>(dst, degi);
  scan1_kernel<<<NB_SCAN, 256, 0, stream>>>(degi, excl, bsum);
  scan23_kernel<<<NB_SCAN, 256, 0, stream>>>(excl, bsum, row_off, cursor);
  mega_kernel<<<FILL_NB + 2 * PREP_NB + EMB_NB, 256, 0, stream>>>(
      src, dst, cursor, csr_src, w0l, w0r, wp0, w1l, w1r, wp1, x_idx, emb, ln0g, ln0b, x);

  // layer 0 (conv epilogue applies LN1, in-place x)
  gather_mean_kernel<<<(NN + 7) / 8, 256, 0, stream>>>(row_off, csr_src, x, af);
  conv_mfma_kernel<<<(NN + 63) / 64, 256, 0, stream>>>(x, af, wp0, b0l, ln1g, ln1b, x, 1);
  // layer 1 (plain relu epilogue, in-place x)
  gather_mean_kernel<<<(NN + 7) / 8, 256, 0, stream>>>(row_off, csr_src, x, af);
  conv_mfma_kernel<<<(NN + 63) / 64, 256, 0, stream>>>(x, af, wp1, b1l, (const float*)0, (const float*)0, x, 0);

  pool_kernel<<<(NN + PCHUNK - 1) / PCHUNK, 128, 0, stream>>>(x, batch, pool, cnt);
  head_kernel<<<NG, 128, 0, stream>>>(pool, cnt, mw1, mb1, mw2, mb2, out);
}

// Round 16
// 393.541 us; speedup vs baseline: 1.3887x; 1.3887x over previous
//
#include <hip/hip_runtime.h>

#define NN 100000
#define NE 600000
#define DIM 128
#define NG 256
#define NGRP 6250   // NN/16
#define NB_SCAN 391  // ceil(NN/256)
#define FILL_NB 2344 // ceil(NE/256)
#define PREP_NB 128
#define EMB_NB 25000 // NN/4

typedef __attribute__((ext_vector_type(8))) short short8_t;
typedef __attribute__((ext_vector_type(4))) float f32x4;

__device__ __forceinline__ ushort f2bf(float f) {
  unsigned u = __float_as_uint(f);
  unsigned r = (u + 0x7fffu + ((u >> 16) & 1u)) >> 16;
  return (ushort)r;
}
__device__ __forceinline__ float bf2f(ushort h) {
  return __uint_as_float(((unsigned)h) << 16);
}

// ---------------- CSR: degree ----------------
__global__ __launch_bounds__(256) void deg_int_kernel(const int* __restrict__ dst,
                                                      int* __restrict__ degi) {
  int e = blockIdx.x * 256 + threadIdx.x;
  if (e < NE) atomicAdd(degi + dst[e], 1);
}

// ---------------- CSR: per-block scan ----------------
__global__ __launch_bounds__(256) void scan1_kernel(const int* __restrict__ degi,
                                                    int* __restrict__ excl,
                                                    int* __restrict__ bsum) {
  __shared__ int tmp[256];
  int t = threadIdx.x;
  int i = blockIdx.x * 256 + t;
  int v = (i < NN) ? degi[i] : 0;
  int val = v;
  tmp[t] = val;
  __syncthreads();
  for (int off = 1; off < 256; off <<= 1) {
    int add = (t >= off) ? tmp[t - off] : 0;
    __syncthreads();
    val += add;
    tmp[t] = val;
    __syncthreads();
  }
  if (i < NN) excl[i] = val - v;
  if (t == 255) bsum[blockIdx.x] = val;
}

// ---------------- CSR: block-offset + row_off + cursor ----------------
__global__ __launch_bounds__(256) void scan23_kernel(const int* __restrict__ excl,
                                                     const int* __restrict__ bsum,
                                                     int* __restrict__ row_off,
                                                     int* __restrict__ cursor) {
  __shared__ int sh[256];
  int blk = blockIdx.x;
  int t = threadIdx.x;
  int partial = 0;
  for (int j = t; j < blk; j += 256) partial += bsum[j];
  sh[t] = partial;
  __syncthreads();
  for (int off = 128; off; off >>= 1) {
    if (t < off) sh[t] += sh[t + off];
    __syncthreads();
  }
  int base = sh[0];
  int i = blk * 256 + t;
  if (i < NN) {
    int r = excl[i] + base;
    row_off[i] = r;
    cursor[i] = r;
  }
  if (i == NN) row_off[NN] = NE;
}

// ---------------- device bodies for the mega kernel ----------------
__device__ __forceinline__ void fill_body(int bid, int t, const int* __restrict__ src,
                                          const int* __restrict__ dst,
                                          int* __restrict__ cursor,
                                          int* __restrict__ csr_src) {
  int e = bid * 256 + t;
  if (e < NE) {
    int d = dst[e];
    int slot = atomicAdd(cursor + d, 1);
    csr_src[slot] = src[e];
  }
}

// wp layout: [p][hl][j][ht][lane][8]; k = p*64 + j*32 + lq*4 + (e&3) + 16*(e>>2);
// k<128 -> wl (agg term, p=0,1), k>=128 -> wr (self term, p=2,3).
__device__ __forceinline__ void prep_body(int idx, const float* __restrict__ wl,
                                          const float* __restrict__ wr,
                                          ushort* __restrict__ wp) {
  int e = idx & 7;
  int lane = (idx >> 3) & 63;
  int ht = (idx >> 9) & 7;
  int j = (idx >> 12) & 1;
  int p = (idx >> 13) & 3;
  int h = ht * 16 + (lane & 15);
  int lq = lane >> 4;
  int k = p * 64 + j * 32 + lq * 4 + (e & 3) + 16 * (e >> 2);
  float v = (k < 128) ? wl[h * 128 + k] : wr[h * 128 + (k - 128)];
  ushort hi = f2bf(v);
  ushort lo = f2bf(v - bf2f(hi));
  wp[(((p * 2 + 0) * 2 + j) * 8 + ht) * 512 + lane * 8 + e] = hi;
  wp[(((p * 2 + 1) * 2 + j) * 8 + ht) * 512 + lane * 8 + e] = lo;
}

__device__ __forceinline__ void embed_body(int bid, int t, const int* __restrict__ x_idx,
                                           const float* __restrict__ emb,
                                           const float* __restrict__ g,
                                           const float* __restrict__ b,
                                           float* __restrict__ out) {
  int wave = t >> 6;
  int lane = t & 63;
  int n = bid * 4 + wave;
  if (n >= NN) return;
  int idx = x_idx[n];
  float2 v = ((const float2*)(emb + (size_t)idx * DIM))[lane];
  float s = v.x + v.y;
  float sq = v.x * v.x + v.y * v.y;
  for (int off = 32; off; off >>= 1) {
    s += __shfl_xor(s, off);
    sq += __shfl_xor(sq, off);
  }
  float m = s * (1.0f / 128.0f);
  float var = sq * (1.0f / 128.0f) - m * m;
  float r = rsqrtf(var + 1e-5f);
  float2 gg = ((const float2*)g)[lane];
  float2 bb = ((const float2*)b)[lane];
  float2 o;
  o.x = (v.x - m) * r * gg.x + bb.x;
  o.y = (v.y - m) * r * gg.y + bb.y;
  ((float2*)(out + (size_t)n * DIM))[lane] = o;
}

// ---------------- mega kernel: fill | prep_w x2 | embed_ln ----------------
__global__ __launch_bounds__(256) void mega_kernel(
    const int* __restrict__ src, const int* __restrict__ dst,
    int* __restrict__ cursor, int* __restrict__ csr_src,
    const float* __restrict__ w0l, const float* __restrict__ w0r, ushort* __restrict__ wp0,
    const float* __restrict__ w1l, const float* __restrict__ w1r, ushort* __restrict__ wp1,
    const int* __restrict__ x_idx, const float* __restrict__ emb,
    const float* __restrict__ ln0g, const float* __restrict__ ln0b,
    float* __restrict__ x) {
  int bid = blockIdx.x;
  int t = threadIdx.x;
  if (bid < FILL_NB) {
    fill_body(bid, t, src, dst, cursor, csr_src);
  } else if (bid < FILL_NB + PREP_NB) {
    prep_body((bid - FILL_NB) * 256 + t, w0l, w0r, wp0);
  } else if (bid < FILL_NB + 2 * PREP_NB) {
    prep_body((bid - FILL_NB - PREP_NB) * 256 + t, w1l, w1r, wp1);
  } else {
    embed_body(bid - FILL_NB - 2 * PREP_NB, t, x_idx, emb, ln0g, ln0b, x);
  }
}

// ---------------- gather mean -> fragment-layout agg (4-wide edge MLP) --------
// af layout (ushort): [g16][jb(4)][lane(64)][hl(2)][e(8)], lane=(lq*16+l15),
// node n = g16*16+l15, k = jb*32 + lq*4 + (e&3) + 16*(e>>2).
// Accumulation order strictly sequential (bit-identical to r14).
__global__ __launch_bounds__(256) void gather_mean_kernel(
    const int* __restrict__ row_off, const int* __restrict__ csr_src,
    const float* __restrict__ x, ushort* __restrict__ af) {
  int t = threadIdx.x;
  int q = t & 31;
  int node = blockIdx.x * 8 + (t >> 5);
  if (node >= NN) return;
  int beg = row_off[node], end = row_off[node + 1];
  float4 acc = make_float4(0.f, 0.f, 0.f, 0.f);
  int e = beg;
  for (; e + 4 <= end; e += 4) {
    int s0 = csr_src[e];
    int s1 = csr_src[e + 1];
    int s2 = csr_src[e + 2];
    int s3 = csr_src[e + 3];
    float4 v0 = ((const float4*)(x + (size_t)s0 * DIM))[q];
    float4 v1 = ((const float4*)(x + (size_t)s1 * DIM))[q];
    float4 v2 = ((const float4*)(x + (size_t)s2 * DIM))[q];
    float4 v3 = ((const float4*)(x + (size_t)s3 * DIM))[q];
    acc.x += v0.x; acc.y += v0.y; acc.z += v0.z; acc.w += v0.w;
    acc.x += v1.x; acc.y += v1.y; acc.z += v1.z; acc.w += v1.w;
    acc.x += v2.x; acc.y += v2.y; acc.z += v2.z; acc.w += v2.w;
    acc.x += v3.x; acc.y += v3.y; acc.z += v3.z; acc.w += v3.w;
  }
  for (; e < end; ++e) {
    int s = csr_src[e];
    float4 v = ((const float4*)(x + (size_t)s * DIM))[q];
    acc.x += v.x; acc.y += v.y; acc.z += v.z; acc.w += v.w;
  }
  float sc = 1.0f / fmaxf((float)(end - beg), 1.0f);
  acc.x *= sc; acc.y *= sc; acc.z *= sc; acc.w *= sc;
  ushort4 hi, lo;
  hi.x = f2bf(acc.x); lo.x = f2bf(acc.x - bf2f(hi.x));
  hi.y = f2bf(acc.y); lo.y = f2bf(acc.y - bf2f(hi.y));
  hi.z = f2bf(acc.z); lo.z = f2bf(acc.z - bf2f(hi.z));
  hi.w = f2bf(acc.w); lo.w = f2bf(acc.w - bf2f(hi.w));
  int g = node >> 4, l15n = node & 15;
  int jb = q >> 3, lqw = q & 3, ebase = q & 4;
  size_t base = (((size_t)g * 4 + jb) * 64 + lqw * 16 + l15n) * 16;
  *(ushort4*)(af + base + ebase) = hi;
  *(ushort4*)(af + base + 8 + ebase) = lo;
}

// ---------------- SAGE conv, TILE=64 (r14-proven version) ----------------
// out = relu([agg|x] @ Wcat^T + bl) (+ optional fused LN), fp32 out.
// Block = 64 nodes, 4 waves, each wave 16 nodes x 128 h. LDS 16 KB.
// Phases 0,1: x self-half staged. Phases 2,3: agg direct from af frags
// (loads INSIDE the loop — r15 lesson: prefetch arrays with runtime index
// lower to VALU selects and double the kernel time).
__global__ __launch_bounds__(256) void conv_mfma_kernel(
    const float* __restrict__ xln, const ushort* __restrict__ af,
    const ushort* __restrict__ wp, const float* __restrict__ bl,
    const float* __restrict__ lng, const float* __restrict__ lnb,
    float* __restrict__ out, int do_ln) {
  __shared__ ushort Xs[2][64 * 64];  // 16 KB
  const int t = threadIdx.x;
  const int lane = t & 63;
  const int wv = t >> 6;
  const int l15 = lane & 15;
  const int lq = lane >> 4;
  const int nbase = blockIdx.x * 64;

  f32x4 acc[8];
#pragma unroll
  for (int b = 0; b < 8; ++b) acc[b] = (f32x4){0.f, 0.f, 0.f, 0.f};

  const int srow = t >> 2;   // staging row 0..63
  const int sq4 = t & 3;     // quad group
  const int gn_s = nbase + srow;
  const bool sval = gn_s < NN;
  char* lds_hi = (char*)&Xs[0][0];
  char* lds_lo = (char*)&Xs[1][0];
  const int sswz = (srow & 7) << 4;

  // ======== phases 0,1: x self-half (staged), W slice pk = ph+2 ========
#pragma unroll 1
  for (int ph = 0; ph < 2; ++ph) {
    if (ph) __syncthreads();
    const int kb = ph * 64;
#pragma unroll
    for (int i = 0; i < 4; ++i) {
      int qd = i * 4 + sq4;
      float4 v = make_float4(0.f, 0.f, 0.f, 0.f);
      if (sval) v = *(const float4*)(xln + (size_t)gn_s * DIM + kb + qd * 4);
      int j = qd >> 3;
      int a = qd & 7;
      int inner = j * 64 + ((a < 4) ? a * 16 : (a - 4) * 16 + 8);
      int off = srow * 128 + inner;
      ushort4 hi, lo;
      hi.x = f2bf(v.x); lo.x = f2bf(v.x - bf2f(hi.x));
      hi.y = f2bf(v.y); lo.y = f2bf(v.y - bf2f(hi.y));
      hi.z = f2bf(v.z); lo.z = f2bf(v.z - bf2f(hi.z));
      hi.w = f2bf(v.w); lo.w = f2bf(v.w - bf2f(hi.w));
      *(ushort4*)(lds_hi + (off ^ sswz)) = hi;
      *(ushort4*)(lds_lo + (off ^ sswz)) = lo;
    }
    __syncthreads();
    const int pk = ph + 2;  // wr half of Wcat
#pragma unroll
    for (int j = 0; j < 2; ++j) {
      int row = wv * 16 + l15;
      int off = row * 128 + j * 64 + lq * 16;
      int sw = (row & 7) << 4;
      short8_t ahi = *(short8_t*)(lds_hi + (off ^ sw));
      short8_t alo = *(short8_t*)(lds_lo + (off ^ sw));
#pragma unroll
      for (int ht = 0; ht < 8; ++ht) {
        short8_t bhi = *(const short8_t*)(wp + (((pk * 2 + 0) * 2 + j) * 8 + ht) * 512 + lane * 8);
        short8_t blo = *(const short8_t*)(wp + (((pk * 2 + 1) * 2 + j) * 8 + ht) * 512 + lane * 8);
        acc[ht] = __builtin_amdgcn_mfma_f32_16x16x32_bf16(ahi, bhi, acc[ht], 0, 0, 0);
        acc[ht] = __builtin_amdgcn_mfma_f32_16x16x32_bf16(alo, bhi, acc[ht], 0, 0, 0);
        acc[ht] = __builtin_amdgcn_mfma_f32_16x16x32_bf16(ahi, blo, acc[ht], 0, 0, 0);
      }
    }
  }

  // ======== phases 2,3: agg half direct from fragments, W slice pk = ph-2 ====
  const int g = blockIdx.x * 4 + wv;
#pragma unroll 1
  for (int ph = 2; ph < 4; ++ph) {
    const int pk = ph - 2;  // wl half of Wcat
#pragma unroll
    for (int j = 0; j < 2; ++j) {
      int jb = (ph & 1) * 2 + j;
      short8_t ahi, alo;
      if (g < NGRP) {
        size_t base = (((size_t)g * 4 + jb) * 64 + lane) * 16;
        ahi = *(const short8_t*)(af + base);
        alo = *(const short8_t*)(af + base + 8);
      } else {
        ahi = (short8_t){0, 0, 0, 0, 0, 0, 0, 0};
        alo = (short8_t){0, 0, 0, 0, 0, 0, 0, 0};
      }
#pragma unroll
      for (int ht = 0; ht < 8; ++ht) {
        short8_t bhi = *(const short8_t*)(wp + (((pk * 2 + 0) * 2 + j) * 8 + ht) * 512 + lane * 8);
        short8_t blo = *(const short8_t*)(wp + (((pk * 2 + 1) * 2 + j) * 8 + ht) * 512 + lane * 8);
        acc[ht] = __builtin_amdgcn_mfma_f32_16x16x32_bf16(ahi, bhi, acc[ht], 0, 0, 0);
        acc[ht] = __builtin_amdgcn_mfma_f32_16x16x32_bf16(alo, bhi, acc[ht], 0, 0, 0);
        acc[ht] = __builtin_amdgcn_mfma_f32_16x16x32_bf16(ahi, blo, acc[ht], 0, 0, 0);
      }
    }
  }

  // ======== epilogue: bias + relu (+ fused LN), fp32 row-major store ========
#pragma unroll
  for (int ht = 0; ht < 8; ++ht) {
    float bv = bl[ht * 16 + l15];
#pragma unroll
    for (int r = 0; r < 4; ++r) acc[ht][r] = fmaxf(acc[ht][r] + bv, 0.f);
  }
  if (do_ln) {
    float gg[8], bb[8];
#pragma unroll
    for (int ht = 0; ht < 8; ++ht) {
      gg[ht] = lng[ht * 16 + l15];
      bb[ht] = lnb[ht * 16 + l15];
    }
#pragma unroll
    for (int r = 0; r < 4; ++r) {
      float s = 0.f, sq = 0.f;
#pragma unroll
      for (int ht = 0; ht < 8; ++ht) {
        float v = acc[ht][r];
        s += v;
        sq += v * v;
      }
#pragma unroll
      for (int msk = 1; msk < 16; msk <<= 1) {
        s += __shfl_xor(s, msk);
        sq += __shfl_xor(sq, msk);
      }
      float m = s * (1.0f / 128.0f);
      float var = sq * (1.0f / 128.0f) - m * m;
      float rstd = rsqrtf(var + 1e-5f);
      int node = nbase + wv * 16 + lq * 4 + r;
      if (node < NN) {
#pragma unroll
        for (int ht = 0; ht < 8; ++ht)
          out[(size_t)node * DIM + ht * 16 + l15] =
              (acc[ht][r] - m) * rstd * gg[ht] + bb[ht];
      }
    }
  } else {
#pragma unroll
    for (int r = 0; r < 4; ++r) {
      int node = nbase + wv * 16 + lq * 4 + r;
      if (node < NN) {
#pragma unroll
        for (int ht = 0; ht < 8; ++ht)
          out[(size_t)node * DIM + ht * 16 + l15] = acc[ht][r];
      }
    }
  }
}

// ---------------- mean pool over sorted batch (short chunks, more TLP) --------
#define PCHUNK 32
__global__ __launch_bounds__(128) void pool_kernel(const float* __restrict__ x,
                                                   const int* __restrict__ batch,
                                                   float* __restrict__ pool,
                                                   float* __restrict__ cnt) {
  int f = threadIdx.x;
  int n0 = blockIdx.x * PCHUNK;
  float acc = 0.f;
  int cur = batch[n0];
  int runlen = 0;
  for (int i = 0; i < PCHUNK; ++i) {
    int n = n0 + i;
    if (n >= NN) break;
    int bg = batch[n];
    if (bg != cur) {
      atomicAdd(&pool[cur * DIM + f], acc);
      if (f == 0) atomicAdd(&cnt[cur], (float)runlen);
      acc = 0.f;
      runlen = 0;
      cur = bg;
    }
    acc += x[(size_t)n * DIM + f];
    runlen++;
  }
  if (runlen > 0) {
    atomicAdd(&pool[cur * DIM + f], acc);
    if (f == 0) atomicAdd(&cnt[cur], (float)runlen);
  }
}

// ---------------- MLP head ----------------
__global__ __launch_bounds__(128) void head_kernel(
    const float* __restrict__ pool, const float* __restrict__ cnt,
    const float* __restrict__ w1, const float* __restrict__ b1,
    const float* __restrict__ w2, const float* __restrict__ b2,
    float* __restrict__ out) {
  __shared__ float gsh[128];
  __shared__ float h[64];
  int g = blockIdx.x;
  int t = threadIdx.x;
  float ic = 1.0f / fmaxf(cnt[g], 1.0f);
  gsh[t] = pool[g * DIM + t] * ic;
  __syncthreads();
  if (t < 64) {
    float a = b1[t];
#pragma unroll 8
    for (int k = 0; k < 128; ++k) a += gsh[k] * w1[t * 128 + k];
    h[t] = fmaxf(a, 0.f);
  }
  __syncthreads();
  if (t < 2) {
    float a = b2[t];
#pragma unroll
    for (int k = 0; k < 64; ++k) a += h[k] * w2[t * 64 + k];
    out[g * 2 + t] = a;
  }
}

extern "C" void kernel_launch(void* const* d_in, const int* in_sizes, int n_in,
                              void* d_out, int out_size, void* d_ws, size_t ws_size,
                              hipStream_t stream) {
  const int* x_idx = (const int*)d_in[0];
  const int* eidx = (const int*)d_in[1];
  const int* batch = (const int*)d_in[2];
  const float* emb = (const float*)d_in[3];
  const float* ln0g = (const float*)d_in[4];
  const float* ln0b = (const float*)d_in[5];
  const float* w0l = (const float*)d_in[6];
  const float* b0l = (const float*)d_in[7];
  const float* w0r = (const float*)d_in[8];
  const float* ln1g = (const float*)d_in[9];
  const float* ln1b = (const float*)d_in[10];
  const float* w1l = (const float*)d_in[11];
  const float* b1l = (const float*)d_in[12];
  const float* w1r = (const float*)d_in[13];
  const float* mw1 = (const float*)d_in[14];
  const float* mb1 = (const float*)d_in[15];
  const float* mw2 = (const float*)d_in[16];
  const float* mb2 = (const float*)d_in[17];
  float* out = (float*)d_out;

  float* ws = (float*)d_ws;
  float* x = ws;                                   // NN*DIM fp32
  ushort* af = (ushort*)(x + (size_t)NN * DIM);    // NN*DIM*2 ushort (frag agg)
  float* pool = (float*)(af + (size_t)NN * DIM * 2);  // NG*DIM
  float* cnt = pool + (size_t)NG * DIM;            // NG
  int* degi = (int*)(cnt + NG);                    // NN (contig for one memset)
  int* excl = degi + NN;                           // NN
  int* row_off = excl + NN;                        // NN+1
  int* cursor = row_off + NN + 1;                  // NN
  int* bsum = cursor + NN;                         // 512
  int* csr_src = bsum + 512;                       // NE
  ushort* wp0 = (ushort*)(csr_src + NE);           // 65536 ushort each
  ushort* wp1 = wp0 + 65536;

  const int* src = eidx;
  const int* dst = eidx + NE;

  // one memset: pool + cnt + degi are contiguous
  hipMemsetAsync(pool, 0, ((size_t)NG * DIM + NG + NN) * sizeof(float), stream);

  deg_int_kernel<<<FILL_NB, 256, 0, stream>>>(dst, degi);
  scan1_kernel<<<NB_SCAN, 256, 0, stream>>>(degi, excl, bsum);
  scan23_kernel<<<NB_SCAN, 256, 0, stream>>>(excl, bsum, row_off, cursor);
  mega_kernel<<<FILL_NB + 2 * PREP_NB + EMB_NB, 256, 0, stream>>>(
      src, dst, cursor, csr_src, w0l, w0r, wp0, w1l, w1r, wp1, x_idx, emb, ln0g, ln0b, x);

  // layer 0 (conv epilogue applies LN1, in-place x)
  gather_mean_kernel<<<(NN + 7) / 8, 256, 0, stream>>>(row_off, csr_src, x, af);
  conv_mfma_kernel<<<(NN + 63) / 64, 256, 0, stream>>>(x, af, wp0, b0l, ln1g, ln1b, x, 1);
  // layer 1 (plain relu epilogue, in-place x)
  gather_mean_kernel<<<(NN + 7) / 8, 256, 0, stream>>>(row_off, csr_src, x, af);
  conv_mfma_kernel<<<(NN + 63) / 64, 256, 0, stream>>>(x, af, wp1, b1l, (const float*)0, (const float*)0, x, 0);

  pool_kernel<<<(NN + PCHUNK - 1) / PCHUNK, 128, 0, stream>>>(x, batch, pool, cnt);
  head_kernel<<<NG, 128, 0, stream>>>(pool, cnt, mw1, mb1, mw2, mb2, out);
}

// Round 17
// 392.159 us; speedup vs baseline: 1.3936x; 1.0035x over previous
//
#include <hip/hip_runtime.h>

#define NN 100000
#define NE 600000
#define DIM 128
#define NG 256
#define NGRP 6250   // NN/16
#define NB_SCAN 391  // ceil(NN/256)
#define FILL_NB 2344 // ceil(NE/256)
#define PREP_NB 128
#define EMB_NB 25000 // NN/4

typedef __attribute__((ext_vector_type(8))) short short8_t;
typedef __attribute__((ext_vector_type(4))) float f32x4;

__device__ __forceinline__ ushort f2bf(float f) {
  unsigned u = __float_as_uint(f);
  unsigned r = (u + 0x7fffu + ((u >> 16) & 1u)) >> 16;
  return (ushort)r;
}
__device__ __forceinline__ float bf2f(ushort h) {
  return __uint_as_float(((unsigned)h) << 16);
}

// ---------------- CSR: degree ----------------
__global__ __launch_bounds__(256) void deg_int_kernel(const int* __restrict__ dst,
                                                      int* __restrict__ degi) {
  int e = blockIdx.x * 256 + threadIdx.x;
  if (e < NE) atomicAdd(degi + dst[e], 1);
}

// ---------------- CSR: per-block scan ----------------
__global__ __launch_bounds__(256) void scan1_kernel(const int* __restrict__ degi,
                                                    int* __restrict__ excl,
                                                    int* __restrict__ bsum) {
  __shared__ int tmp[256];
  int t = threadIdx.x;
  int i = blockIdx.x * 256 + t;
  int v = (i < NN) ? degi[i] : 0;
  int val = v;
  tmp[t] = val;
  __syncthreads();
  for (int off = 1; off < 256; off <<= 1) {
    int add = (t >= off) ? tmp[t - off] : 0;
    __syncthreads();
    val += add;
    tmp[t] = val;
    __syncthreads();
  }
  if (i < NN) excl[i] = val - v;
  if (t == 255) bsum[blockIdx.x] = val;
}

// ---------------- CSR: block-offset + row_off + cursor ----------------
__global__ __launch_bounds__(256) void scan23_kernel(const int* __restrict__ excl,
                                                     const int* __restrict__ bsum,
                                                     int* __restrict__ row_off,
                                                     int* __restrict__ cursor) {
  __shared__ int sh[256];
  int blk = blockIdx.x;
  int t = threadIdx.x;
  int partial = 0;
  for (int j = t; j < blk; j += 256) partial += bsum[j];
  sh[t] = partial;
  __syncthreads();
  for (int off = 128; off; off >>= 1) {
    if (t < off) sh[t] += sh[t + off];
    __syncthreads();
  }
  int base = sh[0];
  int i = blk * 256 + t;
  if (i < NN) {
    int r = excl[i] + base;
    row_off[i] = r;
    cursor[i] = r;
  }
  if (i == NN) row_off[NN] = NE;
}

// ---------------- device bodies for the mega kernel ----------------
__device__ __forceinline__ void fill_body(int bid, int t, const int* __restrict__ src,
                                          const int* __restrict__ dst,
                                          int* __restrict__ cursor,
                                          int* __restrict__ csr_src) {
  int e = bid * 256 + t;
  if (e < NE) {
    int d = dst[e];
    int slot = atomicAdd(cursor + d, 1);
    csr_src[slot] = src[e];
  }
}

// wp layout: [p][hl][j][ht][lane][8]; k = p*64 + j*32 + lq*4 + (e&3) + 16*(e>>2);
// k<128 -> wl (agg term, p=0,1), k>=128 -> wr (self term, p=2,3).
__device__ __forceinline__ void prep_body(int idx, const float* __restrict__ wl,
                                          const float* __restrict__ wr,
                                          ushort* __restrict__ wp) {
  int e = idx & 7;
  int lane = (idx >> 3) & 63;
  int ht = (idx >> 9) & 7;
  int j = (idx >> 12) & 1;
  int p = (idx >> 13) & 3;
  int h = ht * 16 + (lane & 15);
  int lq = lane >> 4;
  int k = p * 64 + j * 32 + lq * 4 + (e & 3) + 16 * (e >> 2);
  float v = (k < 128) ? wl[h * 128 + k] : wr[h * 128 + (k - 128)];
  ushort hi = f2bf(v);
  ushort lo = f2bf(v - bf2f(hi));
  wp[(((p * 2 + 0) * 2 + j) * 8 + ht) * 512 + lane * 8 + e] = hi;
  wp[(((p * 2 + 1) * 2 + j) * 8 + ht) * 512 + lane * 8 + e] = lo;
}

__device__ __forceinline__ void embed_body(int bid, int t, const int* __restrict__ x_idx,
                                           const float* __restrict__ emb,
                                           const float* __restrict__ g,
                                           const float* __restrict__ b,
                                           float* __restrict__ out) {
  int wave = t >> 6;
  int lane = t & 63;
  int n = bid * 4 + wave;
  if (n >= NN) return;
  int idx = x_idx[n];
  float2 v = ((const float2*)(emb + (size_t)idx * DIM))[lane];
  float s = v.x + v.y;
  float sq = v.x * v.x + v.y * v.y;
  for (int off = 32; off; off >>= 1) {
    s += __shfl_xor(s, off);
    sq += __shfl_xor(sq, off);
  }
  float m = s * (1.0f / 128.0f);
  float var = sq * (1.0f / 128.0f) - m * m;
  float r = rsqrtf(var + 1e-5f);
  float2 gg = ((const float2*)g)[lane];
  float2 bb = ((const float2*)b)[lane];
  float2 o;
  o.x = (v.x - m) * r * gg.x + bb.x;
  o.y = (v.y - m) * r * gg.y + bb.y;
  ((float2*)(out + (size_t)n * DIM))[lane] = o;
}

// ---------------- mega kernel: fill | prep_w x2 | embed_ln ----------------
__global__ __launch_bounds__(256) void mega_kernel(
    const int* __restrict__ src, const int* __restrict__ dst,
    int* __restrict__ cursor, int* __restrict__ csr_src,
    const float* __restrict__ w0l, const float* __restrict__ w0r, ushort* __restrict__ wp0,
    const float* __restrict__ w1l, const float* __restrict__ w1r, ushort* __restrict__ wp1,
    const int* __restrict__ x_idx, const float* __restrict__ emb,
    const float* __restrict__ ln0g, const float* __restrict__ ln0b,
    float* __restrict__ x) {
  int bid = blockIdx.x;
  int t = threadIdx.x;
  if (bid < FILL_NB) {
    fill_body(bid, t, src, dst, cursor, csr_src);
  } else if (bid < FILL_NB + PREP_NB) {
    prep_body((bid - FILL_NB) * 256 + t, w0l, w0r, wp0);
  } else if (bid < FILL_NB + 2 * PREP_NB) {
    prep_body((bid - FILL_NB - PREP_NB) * 256 + t, w1l, w1r, wp1);
  } else {
    embed_body(bid - FILL_NB - 2 * PREP_NB, t, x_idx, emb, ln0g, ln0b, x);
  }
}

// ---------------- gather mean -> fragment-layout agg (4-wide edge MLP) --------
// af layout (ushort): [g16][jb(4)][lane(64)][hl(2)][e(8)], lane=(lq*16+l15),
// node n = g16*16+l15, k = jb*32 + lq*4 + (e&3) + 16*(e>>2).
// Accumulation order strictly sequential (bit-identical to r16).
__global__ __launch_bounds__(256) void gather_mean_kernel(
    const int* __restrict__ row_off, const int* __restrict__ csr_src,
    const float* __restrict__ x, ushort* __restrict__ af) {
  int t = threadIdx.x;
  int q = t & 31;
  int node = blockIdx.x * 8 + (t >> 5);
  if (node >= NN) return;
  int beg = row_off[node], end = row_off[node + 1];
  float4 acc = make_float4(0.f, 0.f, 0.f, 0.f);
  int e = beg;
  for (; e + 4 <= end; e += 4) {
    int s0 = csr_src[e];
    int s1 = csr_src[e + 1];
    int s2 = csr_src[e + 2];
    int s3 = csr_src[e + 3];
    float4 v0 = ((const float4*)(x + (size_t)s0 * DIM))[q];
    float4 v1 = ((const float4*)(x + (size_t)s1 * DIM))[q];
    float4 v2 = ((const float4*)(x + (size_t)s2 * DIM))[q];
    float4 v3 = ((const float4*)(x + (size_t)s3 * DIM))[q];
    acc.x += v0.x; acc.y += v0.y; acc.z += v0.z; acc.w += v0.w;
    acc.x += v1.x; acc.y += v1.y; acc.z += v1.z; acc.w += v1.w;
    acc.x += v2.x; acc.y += v2.y; acc.z += v2.z; acc.w += v2.w;
    acc.x += v3.x; acc.y += v3.y; acc.z += v3.z; acc.w += v3.w;
  }
  for (; e < end; ++e) {
    int s = csr_src[e];
    float4 v = ((const float4*)(x + (size_t)s * DIM))[q];
    acc.x += v.x; acc.y += v.y; acc.z += v.z; acc.w += v.w;
  }
  float sc = 1.0f / fmaxf((float)(end - beg), 1.0f);
  acc.x *= sc; acc.y *= sc; acc.z *= sc; acc.w *= sc;
  ushort4 hi, lo;
  hi.x = f2bf(acc.x); lo.x = f2bf(acc.x - bf2f(hi.x));
  hi.y = f2bf(acc.y); lo.y = f2bf(acc.y - bf2f(hi.y));
  hi.z = f2bf(acc.z); lo.z = f2bf(acc.z - bf2f(hi.z));
  hi.w = f2bf(acc.w); lo.w = f2bf(acc.w - bf2f(hi.w));
  int g = node >> 4, l15n = node & 15;
  int jb = q >> 3, lqw = q & 3, ebase = q & 4;
  size_t base = (((size_t)g * 4 + jb) * 64 + lqw * 16 + l15n) * 16;
  *(ushort4*)(af + base + ebase) = hi;
  *(ushort4*)(af + base + 8 + ebase) = lo;
}

// ---------------- SAGE conv, TILE=64, STATIC af prefetch ----------------
// out = relu([agg|x] @ Wcat^T + bl) (+ optional fused LN), fp32 out.
// Block = 64 nodes, 4 waves, each wave 16 nodes x 128 h. LDS 16 KB.
// af fragment loads issued FIRST into individually NAMED registers (rule #20:
// static indexing only — r15's array version lowered to VALU selects).
__global__ __launch_bounds__(256) void conv_mfma_kernel(
    const float* __restrict__ xln, const ushort* __restrict__ af,
    const ushort* __restrict__ wp, const float* __restrict__ bl,
    const float* __restrict__ lng, const float* __restrict__ lnb,
    float* __restrict__ out, int do_ln) {
  __shared__ ushort Xs[2][64 * 64];  // 16 KB
  const int t = threadIdx.x;
  const int lane = t & 63;
  const int wv = t >> 6;
  const int l15 = lane & 15;
  const int lq = lane >> 4;
  const int nbase = blockIdx.x * 64;

  // ---- early af prefetch: named statics, issued before staging ----
  const int g = blockIdx.x * 4 + wv;
  short8_t pa0h, pa0l, pa1h, pa1l, pa2h, pa2l, pa3h, pa3l;
  {
    const short8_t z = (short8_t){0, 0, 0, 0, 0, 0, 0, 0};
    if (g < NGRP) {
      const ushort* ab = af + (size_t)g * 4096 + lane * 16;
      pa0h = *(const short8_t*)(ab + 0 * 1024);
      pa0l = *(const short8_t*)(ab + 0 * 1024 + 8);
      pa1h = *(const short8_t*)(ab + 1 * 1024);
      pa1l = *(const short8_t*)(ab + 1 * 1024 + 8);
      pa2h = *(const short8_t*)(ab + 2 * 1024);
      pa2l = *(const short8_t*)(ab + 2 * 1024 + 8);
      pa3h = *(const short8_t*)(ab + 3 * 1024);
      pa3l = *(const short8_t*)(ab + 3 * 1024 + 8);
    } else {
      pa0h = z; pa0l = z; pa1h = z; pa1l = z;
      pa2h = z; pa2l = z; pa3h = z; pa3l = z;
    }
  }

  f32x4 acc[8];
#pragma unroll
  for (int b = 0; b < 8; ++b) acc[b] = (f32x4){0.f, 0.f, 0.f, 0.f};

  const int srow = t >> 2;   // staging row 0..63
  const int sq4 = t & 3;     // quad group
  const int gn_s = nbase + srow;
  const bool sval = gn_s < NN;
  char* lds_hi = (char*)&Xs[0][0];
  char* lds_lo = (char*)&Xs[1][0];
  const int sswz = (srow & 7) << 4;

  // ======== phases 0,1: x self-half (staged), W slice pk = ph+2 ========
#pragma unroll 1
  for (int ph = 0; ph < 2; ++ph) {
    if (ph) __syncthreads();
    const int kb = ph * 64;
#pragma unroll
    for (int i = 0; i < 4; ++i) {
      int qd = i * 4 + sq4;
      float4 v = make_float4(0.f, 0.f, 0.f, 0.f);
      if (sval) v = *(const float4*)(xln + (size_t)gn_s * DIM + kb + qd * 4);
      int j = qd >> 3;
      int a = qd & 7;
      int inner = j * 64 + ((a < 4) ? a * 16 : (a - 4) * 16 + 8);
      int off = srow * 128 + inner;
      ushort4 hi, lo;
      hi.x = f2bf(v.x); lo.x = f2bf(v.x - bf2f(hi.x));
      hi.y = f2bf(v.y); lo.y = f2bf(v.y - bf2f(hi.y));
      hi.z = f2bf(v.z); lo.z = f2bf(v.z - bf2f(hi.z));
      hi.w = f2bf(v.w); lo.w = f2bf(v.w - bf2f(hi.w));
      *(ushort4*)(lds_hi + (off ^ sswz)) = hi;
      *(ushort4*)(lds_lo + (off ^ sswz)) = lo;
    }
    __syncthreads();
    const int pk = ph + 2;  // wr half of Wcat
#pragma unroll
    for (int j = 0; j < 2; ++j) {
      int row = wv * 16 + l15;
      int off = row * 128 + j * 64 + lq * 16;
      int sw = (row & 7) << 4;
      short8_t ahi = *(short8_t*)(lds_hi + (off ^ sw));
      short8_t alo = *(short8_t*)(lds_lo + (off ^ sw));
#pragma unroll
      for (int ht = 0; ht < 8; ++ht) {
        short8_t bhi = *(const short8_t*)(wp + (((pk * 2 + 0) * 2 + j) * 8 + ht) * 512 + lane * 8);
        short8_t blo = *(const short8_t*)(wp + (((pk * 2 + 1) * 2 + j) * 8 + ht) * 512 + lane * 8);
        acc[ht] = __builtin_amdgcn_mfma_f32_16x16x32_bf16(ahi, bhi, acc[ht], 0, 0, 0);
        acc[ht] = __builtin_amdgcn_mfma_f32_16x16x32_bf16(alo, bhi, acc[ht], 0, 0, 0);
        acc[ht] = __builtin_amdgcn_mfma_f32_16x16x32_bf16(ahi, blo, acc[ht], 0, 0, 0);
      }
    }
  }

  // ======== phases 2,3: agg half from named prefetched fragments ========
  // (pk,j) = (0,0)->pa0, (0,1)->pa1, (1,0)->pa2, (1,1)->pa3 — all static.
#define AGG_STEP(PK, J, AHI, ALO)                                                        \
  {                                                                                      \
    _Pragma("unroll") for (int ht = 0; ht < 8; ++ht) {                                   \
      short8_t bhi = *(const short8_t*)(wp + ((((PK) * 2 + 0) * 2 + (J)) * 8 + ht) * 512 + lane * 8); \
      short8_t blo = *(const short8_t*)(wp + ((((PK) * 2 + 1) * 2 + (J)) * 8 + ht) * 512 + lane * 8); \
      acc[ht] = __builtin_amdgcn_mfma_f32_16x16x32_bf16(AHI, bhi, acc[ht], 0, 0, 0);     \
      acc[ht] = __builtin_amdgcn_mfma_f32_16x16x32_bf16(ALO, bhi, acc[ht], 0, 0, 0);     \
      acc[ht] = __builtin_amdgcn_mfma_f32_16x16x32_bf16(AHI, blo, acc[ht], 0, 0, 0);     \
    }                                                                                    \
  }
  AGG_STEP(0, 0, pa0h, pa0l)
  AGG_STEP(0, 1, pa1h, pa1l)
  AGG_STEP(1, 0, pa2h, pa2l)
  AGG_STEP(1, 1, pa3h, pa3l)
#undef AGG_STEP

  // ======== epilogue: bias + relu (+ fused LN), fp32 row-major store ========
#pragma unroll
  for (int ht = 0; ht < 8; ++ht) {
    float bv = bl[ht * 16 + l15];
#pragma unroll
    for (int r = 0; r < 4; ++r) acc[ht][r] = fmaxf(acc[ht][r] + bv, 0.f);
  }
  if (do_ln) {
    float gg[8], bb[8];
#pragma unroll
    for (int ht = 0; ht < 8; ++ht) {
      gg[ht] = lng[ht * 16 + l15];
      bb[ht] = lnb[ht * 16 + l15];
    }
#pragma unroll
    for (int r = 0; r < 4; ++r) {
      float s = 0.f, sq = 0.f;
#pragma unroll
      for (int ht = 0; ht < 8; ++ht) {
        float v = acc[ht][r];
        s += v;
        sq += v * v;
      }
#pragma unroll
      for (int msk = 1; msk < 16; msk <<= 1) {
        s += __shfl_xor(s, msk);
        sq += __shfl_xor(sq, msk);
      }
      float m = s * (1.0f / 128.0f);
      float var = sq * (1.0f / 128.0f) - m * m;
      float rstd = rsqrtf(var + 1e-5f);
      int node = nbase + wv * 16 + lq * 4 + r;
      if (node < NN) {
#pragma unroll
        for (int ht = 0; ht < 8; ++ht)
          out[(size_t)node * DIM + ht * 16 + l15] =
              (acc[ht][r] - m) * rstd * gg[ht] + bb[ht];
      }
    }
  } else {
#pragma unroll
    for (int r = 0; r < 4; ++r) {
      int node = nbase + wv * 16 + lq * 4 + r;
      if (node < NN) {
#pragma unroll
        for (int ht = 0; ht < 8; ++ht)
          out[(size_t)node * DIM + ht * 16 + l15] = acc[ht][r];
      }
    }
  }
}

// ---------------- mean pool over sorted batch (short chunks, more TLP) --------
#define PCHUNK 32
__global__ __launch_bounds__(128) void pool_kernel(const float* __restrict__ x,
                                                   const int* __restrict__ batch,
                                                   float* __restrict__ pool,
                                                   float* __restrict__ cnt) {
  int f = threadIdx.x;
  int n0 = blockIdx.x * PCHUNK;
  float acc = 0.f;
  int cur = batch[n0];
  int runlen = 0;
  for (int i = 0; i < PCHUNK; ++i) {
    int n = n0 + i;
    if (n >= NN) break;
    int bg = batch[n];
    if (bg != cur) {
      atomicAdd(&pool[cur * DIM + f], acc);
      if (f == 0) atomicAdd(&cnt[cur], (float)runlen);
      acc = 0.f;
      runlen = 0;
      cur = bg;
    }
    acc += x[(size_t)n * DIM + f];
    runlen++;
  }
  if (runlen > 0) {
    atomicAdd(&pool[cur * DIM + f], acc);
    if (f == 0) atomicAdd(&cnt[cur], (float)runlen);
  }
}

// ---------------- MLP head ----------------
__global__ __launch_bounds__(128) void head_kernel(
    const float* __restrict__ pool, const float* __restrict__ cnt,
    const float* __restrict__ w1, const float* __restrict__ b1,
    const float* __restrict__ w2, const float* __restrict__ b2,
    float* __restrict__ out) {
  __shared__ float gsh[128];
  __shared__ float h[64];
  int g = blockIdx.x;
  int t = threadIdx.x;
  float ic = 1.0f / fmaxf(cnt[g], 1.0f);
  gsh[t] = pool[g * DIM + t] * ic;
  __syncthreads();
  if (t < 64) {
    float a = b1[t];
#pragma unroll 8
    for (int k = 0; k < 128; ++k) a += gsh[k] * w1[t * 128 + k];
    h[t] = fmaxf(a, 0.f);
  }
  __syncthreads();
  if (t < 2) {
    float a = b2[t];
#pragma unroll
    for (int k = 0; k < 64; ++k) a += h[k] * w2[t * 64 + k];
    out[g * 2 + t] = a;
  }
}

extern "C" void kernel_launch(void* const* d_in, const int* in_sizes, int n_in,
                              void* d_out, int out_size, void* d_ws, size_t ws_size,
                              hipStream_t stream) {
  const int* x_idx = (const int*)d_in[0];
  const int* eidx = (const int*)d_in[1];
  const int* batch = (const int*)d_in[2];
  const float* emb = (const float*)d_in[3];
  const float* ln0g = (const float*)d_in[4];
  const float* ln0b = (const float*)d_in[5];
  const float* w0l = (const float*)d_in[6];
  const float* b0l = (const float*)d_in[7];
  const float* w0r = (const float*)d_in[8];
  const float* ln1g = (const float*)d_in[9];
  const float* ln1b = (const float*)d_in[10];
  const float* w1l = (const float*)d_in[11];
  const float* b1l = (const float*)d_in[12];
  const float* w1r = (const float*)d_in[13];
  const float* mw1 = (const float*)d_in[14];
  const float* mb1 = (const float*)d_in[15];
  const float* mw2 = (const float*)d_in[16];
  const float* mb2 = (const float*)d_in[17];
  float* out = (float*)d_out;

  float* ws = (float*)d_ws;
  float* x = ws;                                   // NN*DIM fp32
  ushort* af = (ushort*)(x + (size_t)NN * DIM);    // NN*DIM*2 ushort (frag agg)
  float* pool = (float*)(af + (size_t)NN * DIM * 2);  // NG*DIM
  float* cnt = pool + (size_t)NG * DIM;            // NG
  int* degi = (int*)(cnt + NG);                    // NN (contig for one memset)
  int* excl = degi + NN;                           // NN
  int* row_off = excl + NN;                        // NN+1
  int* cursor = row_off + NN + 1;                  // NN
  int* bsum = cursor + NN;                         // 512
  int* csr_src = bsum + 512;                       // NE
  ushort* wp0 = (ushort*)(csr_src + NE);           // 65536 ushort each
  ushort* wp1 = wp0 + 65536;

  const int* src = eidx;
  const int* dst = eidx + NE;

  // one memset: pool + cnt + degi are contiguous
  hipMemsetAsync(pool, 0, ((size_t)NG * DIM + NG + NN) * sizeof(float), stream);

  deg_int_kernel<<<FILL_NB, 256, 0, stream>>>(dst, degi);
  scan1_kernel<<<NB_SCAN, 256, 0, stream>>>(degi, excl, bsum);
  scan23_kernel<<<NB_SCAN, 256, 0, stream>>>(excl, bsum, row_off, cursor);
  mega_kernel<<<FILL_NB + 2 * PREP_NB + EMB_NB, 256, 0, stream>>>(
      src, dst, cursor, csr_src, w0l, w0r, wp0, w1l, w1r, wp1, x_idx, emb, ln0g, ln0b, x);

  // layer 0 (conv epilogue applies LN1, in-place x)
  gather_mean_kernel<<<(NN + 7) / 8, 256, 0, stream>>>(row_off, csr_src, x, af);
  conv_mfma_kernel<<<(NN + 63) / 64, 256, 0, stream>>>(x, af, wp0, b0l, ln1g, ln1b, x, 1);
  // layer 1 (plain relu epilogue, in-place x)
  gather_mean_kernel<<<(NN + 7) / 8, 256, 0, stream>>>(row_off, csr_src, x, af);
  conv_mfma_kernel<<<(NN + 63) / 64, 256, 0, stream>>>(x, af, wp1, b1l, (const float*)0, (const float*)0, x, 0);

  pool_kernel<<<(NN + PCHUNK - 1) / PCHUNK, 128, 0, stream>>>(x, batch, pool, cnt);
  head_kernel<<<NG, 128, 0, stream>>>(pool, cnt, mw1, mb1, mw2, mb2, out);
}